// Round 1
// 340.135 us; speedup vs baseline: 1.0284x; 1.0284x over previous
//
#include <hip/hip_runtime.h>
#include <math.h>

#define B_TOT 32768
#define NPB 4                 // one wave = one batch element, 4 per block

// conv1 tile: transposed [w][h][d] rows; stride 132 floats (126 used), 16B-aligned.
// Layout: rows 0..3 = w0 h0..h3, rows 4..7 = w1 h0..h3, row 8 = shared zero row.
#define RS1 132
#define W1S (4 * RS1)         // 528 : w-stride
#define ZROW (8 * RS1)        // 1056: zero row (stays zero; h-halo + conv2 halo reads)
#define XS_SZ 1216            // 9*132 = 1188, rounded to float4 multiple

// pool1 tile aliased into dead x region after conv1: [w][h][dd], stride 37 (odd)
#define P_RS 37               // rows 0..7 -> floats [0,296)
#define F2_OFF 320            // 80 floats, float4-aligned for vectorized fcm1 reads
#define V11_OFF 400           // 11 floats

typedef float vf4 __attribute__((ext_vector_type(4)));
typedef float vf2 __attribute__((ext_vector_type(2)));

// wave-level sync: buffers are wave-private; avoid s_barrier's vmcnt(0) drain
__device__ __forceinline__ void wave_sync() {
    __builtin_amdgcn_s_waitcnt(0xC07F);    // lgkmcnt(0) only (vm/exp left pending)
    __builtin_amdgcn_wave_barrier();
}

__global__ __launch_bounds__(256, 8) void encoder_kernel(
    const float* __restrict__ x1, const float* __restrict__ x2,
    const float* __restrict__ w1, const float* __restrict__ b1,
    const float* __restrict__ w2, const float* __restrict__ b2,
    const float* __restrict__ fcm1_w, const float* __restrict__ fcm1_b,
    const float* __restrict__ fc_w, const float* __restrict__ fc_b,
    float* __restrict__ out)
{
    __shared__ __align__(16) float xs[NPB][XS_SZ];   // 19456 B/block -> 8 blocks/CU

    const int tid  = threadIdx.x;
    const int wv   = tid >> 6, lane = tid & 63;
    const long b   = (long)blockIdx.x * NPB + wv;

    // output layout (flat f32, tuple order: z, aug_xm, aug_x_sd, pool1_idx, pool2_idx)
    const size_t XM0 = (size_t)B_TOT * 100;
    const size_t SD0 = XM0 + (size_t)B_TOT * 960;
    const size_t P10 = SD0 + (size_t)B_TOT;
    const size_t P20 = P10 + (size_t)B_TOT * 240;

    // ---- conv weights: uniform loads -> SGPRs (s_load) ----
    float w1r[21], w2r[21];
    #pragma unroll
    for (int k = 0; k < 21; k++) { w1r[k] = w1[k]; w2r[k] = w2[k]; }
    const float bb1 = b1[0], bb2 = b2[0];

    // ---- zero entire tile (d-halos + zero row) ----
    {
        const vf4 z4 = (vf4){0.f, 0.f, 0.f, 0.f};
        vf4* xz = (vf4*)xs[wv];
        #pragma unroll
        for (int t = 0; t < 5; t++) { int i = lane + 64 * t; if (i < XS_SZ / 4) xz[i] = z4; }
    }
    wave_sync();

    // ---- stage x1 -> LDS (transposed scatter) + aug_xm passthrough (NT store) ----
    {
        const vf4* xin = (const vf4*)(x1 + b * 960);
        vf4*       xo  = (vf4*)(out + XM0 + b * 960);
        #pragma unroll
        for (int t = 0; t < 4; t++) {
            int i = lane + 64 * t;                 // 240 float4 per batch
            if (i < 240) {
                vf4 v = xin[i];
                __builtin_nontemporal_store(v, &xo[i]);
                // float4 covers e=4i..4i+3: d = i>>1, h = 2*(i&1)+(c>>1), w = c&1
                int bd = (i >> 1) + 3;             // d-halo offset +3
                int hb = 2 * (i & 1);
                xs[wv][ hb      * RS1       + bd] = v.x;   // w=0
                xs[wv][ hb      * RS1 + W1S + bd] = v.y;   // w=1
                xs[wv][(hb + 1) * RS1       + bd] = v.z;
                xs[wv][(hb + 1) * RS1 + W1S + bd] = v.w;
            }
        }
    }
    wave_sync();

    // ---- conv1 (7,3,1) pad(3,1,0) + ReLU + maxpool D/4 (+indices) ----
    // pooled values stay in regs; p1 tile written after sync (aliases x region)
    float pv[4];
    #pragma unroll
    for (int t = 0; t < 4; t++) {
        int p = lane + 64 * t;                     // 240 pooled outputs
        float best = 0.f;
        if (p < 240) {
            int dd = p >> 3, h = (p >> 1) & 3, w = p & 1;
            int d0 = 4 * dd;                       // aligned read base (x-index 4dd-3)
            float va[3][10];
            #pragma unroll
            for (int kh = 0; kh < 3; kh++) {
                int r = h + kh - 1;
                int base = ((unsigned)r < 4u) ? (w * W1S + r * RS1 + d0) : (ZROW + d0);
                const float* bp = &xs[wv][base];   // 16B aligned: all terms %4==0
                vf4 q0 = *(const vf4*)bp;
                vf4 q1 = *(const vf4*)(bp + 4);
                vf2 q2 = *(const vf2*)(bp + 8);
                va[kh][0]=q0.x; va[kh][1]=q0.y; va[kh][2]=q0.z; va[kh][3]=q0.w;
                va[kh][4]=q1.x; va[kh][5]=q1.y; va[kh][6]=q1.z; va[kh][7]=q1.w;
                va[kh][8]=q2.x; va[kh][9]=q2.y;
            }
            int bj = 0;
            #pragma unroll
            for (int j = 0; j < 4; j++) {
                float acc = bb1;
                #pragma unroll
                for (int kd = 0; kd < 7; kd++)
                    #pragma unroll
                    for (int kh = 0; kh < 3; kh++)
                        acc = fmaf(va[kh][j + kd], w1r[kd * 3 + kh], acc);
                acc = fmaxf(acc, 0.f);
                if (j == 0)          { best = acc; }
                else if (acc > best) { best = acc; bj = j; }   // first-max tiebreak
            }
            __builtin_nontemporal_store(
                (float)(((dd * 4 + bj) * 4 + h) * 2 + w), &out[P10 + b * 240 + p]);
        }
        pv[t] = best;
    }
    wave_sync();

    // ---- write p1 tile into dead x region: halo zeros + pooled values ----
    if (lane < 48) {                               // 8 rows x 6 halo floats
        int row = lane / 6, pos = lane - row * 6;
        xs[wv][row * P_RS + (pos < 3 ? pos : pos + 30)] = 0.f;
    }
    #pragma unroll
    for (int t = 0; t < 4; t++) {
        int p = lane + 64 * t;
        if (p < 240) {
            int dd = p >> 3, h = (p >> 1) & 3, w = p & 1;
            xs[wv][(4 * w + h) * P_RS + dd + 3] = pv[t];
        }
    }
    wave_sync();

    // ---- conv2 + ReLU + maxpool D/3 (+indices) ----
    #pragma unroll
    for (int t = 0; t < 2; t++) {
        int p = lane + 64 * t;                     // 80 pooled outputs
        if (p < 80) {
            int dd = p >> 3, h = (p >> 1) & 3, w = p & 1;
            int d0 = 3 * dd;
            float va[3][9];
            #pragma unroll
            for (int kh = 0; kh < 3; kh++) {
                int r = h + kh - 1;
                int base = ((unsigned)r < 4u) ? ((4 * w + r) * P_RS + d0) : (ZROW + d0);
                #pragma unroll
                for (int c = 0; c < 9; c++) va[kh][c] = xs[wv][base + c];
            }
            float best = 0.f; int bj = 0;
            #pragma unroll
            for (int j = 0; j < 3; j++) {
                float acc = bb2;
                #pragma unroll
                for (int kd = 0; kd < 7; kd++)
                    #pragma unroll
                    for (int kh = 0; kh < 3; kh++)
                        acc = fmaf(va[kh][j + kd], w2r[kd * 3 + kh], acc);
                acc = fmaxf(acc, 0.f);
                if (j == 0)          { best = acc; }
                else if (acc > best) { best = acc; bj = j; }
            }
            xs[wv][F2_OFF + p] = best;             // disjoint from p1 rows: no hazard
            __builtin_nontemporal_store(
                (float)(((dd * 3 + bj) * 4 + h) * 2 + w), &out[P20 + b * 80 + p]);
        }
    }
    wave_sync();

    // ---- fcm1 (80->10, 4-way split) + ELU; sigmoid(x2). Weights direct from L2. ----
    if (lane < 40) {
        int o = lane >> 2, q = lane & 3;
        const vf4* fp = (const vf4*)&xs[wv][F2_OFF + q * 20];   // 16B aligned
        const vf4* wp = (const vf4*)(fcm1_w + o * 80 + q * 20); // 16B aligned, L2-hot
        float acc = 0.f;
        #pragma unroll
        for (int k = 0; k < 5; k++) {
            vf4 a = fp[k], c = wp[k];
            acc = fmaf(a.x, c.x, fmaf(a.y, c.y, fmaf(a.z, c.z, fmaf(a.w, c.w, acc))));
        }
        acc += __shfl_xor(acc, 1);
        acc += __shfl_xor(acc, 2);
        if (q == 0) {
            acc += fcm1_b[o];
            xs[wv][V11_OFF + o] = (acc > 0.f) ? acc : expm1f(acc);   // ELU
        }
    } else if (lane == 40) {
        float xv = x2[b];
        xs[wv][V11_OFF + 10] = 1.f / (1.f + expf(-xv));
        __builtin_nontemporal_store(xv, &out[SD0 + b]);
    }
    wave_sync();

    // ---- fc (11->100) + BN-eval scale ----
    {
        float fw0[11], fw1[11], fb0, fb1 = 0.f;
        #pragma unroll
        for (int k = 0; k < 11; k++) { fw0[k] = fc_w[lane * 11 + k]; fw1[k] = 0.f; }
        fb0 = fc_b[lane];
        if (lane < 36) {
            #pragma unroll
            for (int k = 0; k < 11; k++) fw1[k] = fc_w[(64 + lane) * 11 + k];
            fb1 = fc_b[64 + lane];
        }
        const float scale = 0.9999950000374997f;   // 1/sqrt(1+1e-5)
        float vv[11];
        #pragma unroll
        for (int i = 0; i < 11; i++) vv[i] = xs[wv][V11_OFF + i];  // broadcast reads
        float a0 = fb0;
        #pragma unroll
        for (int i = 0; i < 11; i++) a0 = fmaf(vv[i], fw0[i], a0);
        __builtin_nontemporal_store(a0 * scale, &out[b * 100 + lane]);
        if (lane < 36) {
            float a1 = fb1;
            #pragma unroll
            for (int i = 0; i < 11; i++) a1 = fmaf(vv[i], fw1[i], a1);
            __builtin_nontemporal_store(a1 * scale, &out[b * 100 + 64 + lane]);
        }
    }
}

extern "C" void kernel_launch(void* const* d_in, const int* in_sizes, int n_in,
                              void* d_out, int out_size, void* d_ws, size_t ws_size,
                              hipStream_t stream) {
    const float* x1     = (const float*)d_in[0];
    const float* x2     = (const float*)d_in[1];
    const float* w1     = (const float*)d_in[4];
    const float* b1     = (const float*)d_in[5];
    const float* w2     = (const float*)d_in[6];
    const float* b2     = (const float*)d_in[7];
    const float* fcm1_w = (const float*)d_in[8];
    const float* fcm1_b = (const float*)d_in[9];
    const float* fc_w   = (const float*)d_in[10];
    const float* fc_b   = (const float*)d_in[11];
    float* out = (float*)d_out;

    dim3 grid(B_TOT / NPB), block(256);
    encoder_kernel<<<grid, block, 0, stream>>>(x1, x2, w1, b1, w2, b2,
                                               fcm1_w, fcm1_b, fc_w, fc_b, out);
}